// Round 7
// baseline (200.397 us; speedup 1.0000x reference)
//
#include <hip/hip_runtime.h>
#include <math.h>

#define LENGTH 4096
#define BATCH  4096
#define CHUNK  16      // timesteps per thread
#define NTHR   256     // threads per block; NTHR*CHUNK == LENGTH (one block per row)
#define NWAVE  (NTHR / 64)

typedef float vf4 __attribute__((ext_vector_type(4)));

// max-plus 2x2 compose: D = A (x) B, D[k][l] = max_m A[k][m] + B[m][l]
__device__ __forceinline__ void mp_compose(
    float a00, float a01, float a10, float a11,
    float b00, float b01, float b10, float b11,
    float& d00, float& d01, float& d10, float& d11) {
  d00 = fmaxf(a00 + b00, a01 + b10);
  d01 = fmaxf(a00 + b01, a01 + b11);
  d10 = fmaxf(a10 + b00, a11 + b10);
  d11 = fmaxf(a10 + b01, a11 + b11);
}

// F <- (S (x) D_u) (x) F     (one timestep applied on the left)
__device__ __forceinline__ void mp_step(
    float& f00, float& f01, float& f10, float& f11, float ui, float q) {
  float a0l0 = f00 - ui, a1l0 = f10 + ui;  // a_m[l] = phi_m + F[m][l]
  float a0l1 = f01 - ui, a1l1 = f11 + ui;
  float n00 = fmaxf(a0l0 + q, a1l0 - q);
  float n10 = fmaxf(a0l0 - q, a1l0 + q);
  float n01 = fmaxf(a0l1 + q, a1l1 - q);
  float n11 = fmaxf(a0l1 - q, a1l1 + q);
  f00 = n00; f01 = n01; f10 = n10; f11 = n11;
}

__global__ __launch_bounds__(NTHR, 8) void chain_bp_kernel(
    const float* __restrict__ jp, const float* __restrict__ bp,
    const int* __restrict__ obs, float* __restrict__ out) {
  const int row  = blockIdx.x;
  const int tid  = threadIdx.x;
  const int lane = tid & 63;
  const int wv   = tid >> 6;

  // All potentials pre-scaled by log2(e): outputs use raw v_exp_f32 (2^x).
  const float LOG2E = 1.44269504088896f;
  const float j  = jp[0];
  const float q  = 0.25f * j * LOG2E;      // log2 psi diag; off-diag = -q
  const float u0 = 0.5f * bp[0] * LOG2E;   // log2 phi[o=0][s=1] ; s=0 is -u
  const float u1 = 0.5f * bp[1] * LOG2E;
  const float wb = -fabsf(q);              // w_base: 0vec == S (x) (wb,wb)

  // ---- LDS: chunk-matrix LUTs + stitch scratch ----
  __shared__ vf4 lut4s[16];
  __shared__ vf4 lut8[256];
  __shared__ float smp[NWAVE][4];  // per-wave full prefix matrix
  __shared__ float sms[NWAVE][4];  // per-wave full suffix matrix

  // ---- load this thread's 16 observations -> u[i], two 8-bit indices ----
  const int t0 = tid * CHUNK;
  const int4* op = reinterpret_cast<const int4*>(obs + (size_t)row * LENGTH + t0);
  int4 o0 = op[0], o1 = op[1], o2 = op[2], o3 = op[3];
  float u[CHUNK];
  u[0]=o0.x?u1:u0;  u[1]=o0.y?u1:u0;  u[2]=o0.z?u1:u0;  u[3]=o0.w?u1:u0;
  u[4]=o1.x?u1:u0;  u[5]=o1.y?u1:u0;  u[6]=o1.z?u1:u0;  u[7]=o1.w?u1:u0;
  u[8]=o2.x?u1:u0;  u[9]=o2.y?u1:u0;  u[10]=o2.z?u1:u0; u[11]=o2.w?u1:u0;
  u[12]=o3.x?u1:u0; u[13]=o3.y?u1:u0; u[14]=o3.z?u1:u0; u[15]=o3.w?u1:u0;
  // bit k = obs at in-chunk step (base+k); step 0 is rightmost factor
  int idxlo = o0.x | (o0.y<<1) | (o0.z<<2) | (o0.w<<3)
            | (o1.x<<4) | (o1.y<<5) | (o1.z<<6) | (o1.w<<7);
  int idxhi = o2.x | (o2.y<<1) | (o2.z<<2) | (o2.w<<3)
            | (o3.x<<4) | (o3.y<<5) | (o3.z<<6) | (o3.w<<7);

  // ---- build 4-bit LUT (16 threads), then 8-bit LUT (256 threads) ----
  if (tid < 16) {
    float ua = (tid & 1) ? u1 : u0;
    float f00 = -ua + q, f01 = ua - q, f10 = -ua - q, f11 = ua + q;
#pragma unroll
    for (int k = 1; k < 4; ++k)
      mp_step(f00, f01, f10, f11, ((tid >> k) & 1) ? u1 : u0, q);
    lut4s[tid] = (vf4){f00, f01, f10, f11};
  }
  __syncthreads();
  {
    vf4 a = lut4s[tid >> 4], c = lut4s[tid & 15];
    float d00, d01, d10, d11;
    mp_compose(a[0], a[1], a[2], a[3], c[0], c[1], c[2], c[3], d00, d01, d10, d11);
    lut8[tid] = (vf4){d00, d01, d10, d11};
  }
  __syncthreads();

  // ---- chunk forward matrix F (16 steps) = lut8[hi] (x) lut8[lo] ----
  float f00, f01, f10, f11;
  {
    vf4 a = lut8[idxhi], c = lut8[idxlo];
    mp_compose(a[0], a[1], a[2], a[3], c[0], c[1], c[2], c[3], f00, f01, f10, f11);
  }

  // ---- interleaved wave scans: prefix X over F, suffix Y over F^T ----
  float x00 = f00, x01 = f01, x10 = f10, x11 = f11;
  float y00 = f00, y01 = f10, y10 = f01, y11 = f11;  // transpose
#pragma unroll
  for (int d = 1; d < 64; d <<= 1) {
    float px00 = __shfl_up(x00, d), px01 = __shfl_up(x01, d);
    float px10 = __shfl_up(x10, d), px11 = __shfl_up(x11, d);
    float py00 = __shfl_down(y00, d), py01 = __shfl_down(y01, d);
    float py10 = __shfl_down(y10, d), py11 = __shfl_down(y11, d);
    if (lane >= d) {
      float n00, n01, n10, n11;
      mp_compose(x00, x01, x10, x11, px00, px01, px10, px11, n00, n01, n10, n11);
      x00 = n00; x01 = n01; x10 = n10; x11 = n11;
    }
    if (lane + d < 64) {
      float n00, n01, n10, n11;
      mp_compose(y00, y01, y10, y11, py00, py01, py10, py11, n00, n01, n10, n11);
      y00 = n00; y01 = n01; y10 = n10; y11 = n11;
    }
  }

  // ---- cross-wave stitch ----
  if (lane == 63) { smp[wv][0] = x00; smp[wv][1] = x01; smp[wv][2] = x10; smp[wv][3] = x11; }
  if (lane == 0)  { sms[wv][0] = y00; sms[wv][1] = y01; sms[wv][2] = y10; sms[wv][3] = y11; }
  __syncthreads();

  // fhead = W_{wv-1} (x) ... (x) W_0 (x) 0vec
  float fh0 = 0.f, fh1 = 0.f;
  for (int k = 0; k < wv; ++k) {
    float m00 = smp[k][0], m01 = smp[k][1], m10 = smp[k][2], m11 = smp[k][3];
    float n0 = fmaxf(m00 + fh0, m01 + fh1);
    float n1 = fmaxf(m10 + fh0, m11 + fh1);
    fh0 = n0; fh1 = n1;
  }
  // wtail = V_{wv+1} (x) ... (x) V_{NWAVE-1} (x) w_base
  float wt0 = wb, wt1 = wb;
  for (int k = NWAVE - 1; k > wv; --k) {
    float m00 = sms[k][0], m01 = sms[k][1], m10 = sms[k][2], m11 = sms[k][3];
    float n0 = fmaxf(m00 + wt0, m01 + wt1);
    float n1 = fmaxf(m10 + wt0, m11 + wt1);
    wt0 = n0; wt1 = n1;
  }

  // z_c = X_c (x) fhead = global fwd at start of NEXT chunk; f_in = z_{c-1}
  float z0 = fmaxf(x00 + fh0, x01 + fh1);
  float z1 = fmaxf(x10 + fh0, x11 + fh1);
  float zp0 = __shfl_up(z0, 1), zp1 = __shfl_up(z1, 1);
  float fi0 = (lane == 0) ? fh0 : zp0;
  float fi1 = (lane == 0) ? fh1 : zp1;

  // y_c = Y_c (x) wtail = w_{c-1}; w_c = y_{c+1} (lane 63 -> wtail)
  float yv0 = fmaxf(y00 + wt0, y01 + wt1);
  float yv1 = fmaxf(y10 + wt0, y11 + wt1);
  float yn0 = __shfl_down(yv0, 1), yn1 = __shfl_down(yv1, 1);
  float wc0 = (lane == 63) ? wt0 : yn0;
  float wc1 = (lane == 63) ? wt1 : yn1;
  // g = bwd at last t of this chunk = S (x) w_c
  float g0 = fmaxf(q + wc0, -q + wc1);
  float g1 = fmaxf(-q + wc0, q + wc1);

  // ---- backward sweep with checkpoints every 4 steps (8 regs total) ----
  // ck[s] = bwd message at in-chunk position 4s+3
  float ck0[4], ck1[4];
  ck0[3] = g0; ck1[3] = g1;
  {
    float r0 = g0, r1 = g1;
#pragma unroll
    for (int i = CHUNK - 1; i >= 4; --i) {
      // bwd[i-1] = M_i (x) bwd[i]
      float a0 = r0 - u[i], a1 = r1 + u[i];
      r0 = fmaxf(a0 + q, a1 - q);
      r1 = fmaxf(a0 - q, a1 + q);
      if (((i - 1) & 3) == 3) { ck0[(i - 1) >> 2] = r0; ck1[(i - 1) >> 2] = r1; }
    }
  }

  // ---- forward/belief pass, 4-step segments; store 16B per plane/segment ----
  float* outp = out + (size_t)row * (2 * LENGTH) + t0;
  float fw0 = fi0, fw1 = fi1;
#pragma unroll
  for (int s = 0; s < 4; ++s) {
    // reconstruct bwd for positions 4s..4s+3 from ck[s] (= bwd at 4s+3)
    float w0[4], w1[4];
    w0[3] = ck0[s]; w1[3] = ck1[s];
#pragma unroll
    for (int k = 3; k > 0; --k) {
      float a0 = w0[k] - u[4 * s + k], a1 = w1[k] + u[4 * s + k];
      w0[k - 1] = fmaxf(a0 + q, a1 - q);
      w1[k - 1] = fmaxf(a0 - q, a1 + q);
    }
    vf4 s0v, s1v;
#pragma unroll
    for (int k = 0; k < 4; ++k) {
      float ui = u[4 * s + k];
      s0v[k] = __builtin_amdgcn_exp2f(-ui + fw0 + w0[k]);
      s1v[k] = __builtin_amdgcn_exp2f( ui + fw1 + w1[k]);
      float a0 = fw0 - ui, a1 = fw1 + ui;
      fw0 = fmaxf(a0 + q, a1 - q);
      fw1 = fmaxf(a0 - q, a1 + q);
    }
    *reinterpret_cast<vf4*>(outp + 4 * s)          = s0v;
    *reinterpret_cast<vf4*>(outp + LENGTH + 4 * s) = s1v;
  }
}

extern "C" void kernel_launch(void* const* d_in, const int* in_sizes, int n_in,
                              void* d_out, int out_size, void* d_ws, size_t ws_size,
                              hipStream_t stream) {
  const float* jp  = (const float*)d_in[0];   // scalar j
  const float* bp  = (const float*)d_in[1];   // b[2]
  const int*   obs = (const int*)d_in[2];     // [BATCH, LENGTH] int32
  float* out = (float*)d_out;                 // [BATCH, 2, LENGTH] fp32

  chain_bp_kernel<<<BATCH, NTHR, 0, stream>>>(jp, bp, obs, out);
}

// Round 8
// 194.826 us; speedup vs baseline: 1.0286x; 1.0286x over previous
//
#include <hip/hip_runtime.h>
#include <math.h>

#define LENGTH 4096
#define BATCH  4096
#define CHUNK  8       // timesteps per thread
#define NTHR   512     // threads per block; NTHR*CHUNK == LENGTH (one row-stream)
#define NWAVE  (NTHR / 64)
#define RPB    2       // rows per block
#define GRID   (BATCH / RPB)

typedef float vf4 __attribute__((ext_vector_type(4)));

// max-plus 2x2 compose: D = A (x) B, D[k][l] = max_m A[k][m] + B[m][l]
__device__ __forceinline__ void mp_compose(
    float a00, float a01, float a10, float a11,
    float b00, float b01, float b10, float b11,
    float& d00, float& d01, float& d10, float& d11) {
  d00 = fmaxf(a00 + b00, a01 + b10);
  d01 = fmaxf(a00 + b01, a01 + b11);
  d10 = fmaxf(a10 + b00, a11 + b10);
  d11 = fmaxf(a10 + b01, a11 + b11);
}

// F <- (S (x) D_u) (x) F     (one timestep applied on the left)
__device__ __forceinline__ void mp_step(
    float& f00, float& f01, float& f10, float& f11, float ui, float q) {
  float a0l0 = f00 - ui, a1l0 = f10 + ui;
  float a0l1 = f01 - ui, a1l1 = f11 + ui;
  float n00 = fmaxf(a0l0 + q, a1l0 - q);
  float n10 = fmaxf(a0l0 - q, a1l0 + q);
  float n01 = fmaxf(a0l1 + q, a1l1 - q);
  float n11 = fmaxf(a0l1 - q, a1l1 + q);
  f00 = n00; f01 = n01; f10 = n10; f11 = n11;
}

// backward + forward sweep over one 8-step chunk, with exp2 beliefs + stores
__device__ __forceinline__ void sweep_store(
    const float* u, float fi0, float fi1, float g0, float g1,
    float q, float* outp) {
  float b0[CHUNK], b1[CHUNK];
  b0[CHUNK - 1] = g0; b1[CHUNK - 1] = g1;
#pragma unroll
  for (int i = CHUNK - 1; i > 0; --i) {
    float a0 = b0[i] - u[i], a1 = b1[i] + u[i];
    b0[i - 1] = fmaxf(a0 + q, a1 - q);
    b1[i - 1] = fmaxf(a0 - q, a1 + q);
  }
  float fw0 = fi0, fw1 = fi1;
  vf4 p0lo, p0hi, p1lo, p1hi;
#pragma unroll
  for (int i = 0; i < CHUNK; ++i) {
    float ui = u[i];
    float e0 = __builtin_amdgcn_exp2f(-ui + fw0 + b0[i]);
    float e1 = __builtin_amdgcn_exp2f( ui + fw1 + b1[i]);
    if (i < 4) { p0lo[i] = e0; p1lo[i] = e1; }
    else       { p0hi[i - 4] = e0; p1hi[i - 4] = e1; }
    float a0 = fw0 - ui, a1 = fw1 + ui;
    fw0 = fmaxf(a0 + q, a1 - q);
    fw1 = fmaxf(a0 - q, a1 + q);
  }
  *reinterpret_cast<vf4*>(outp)              = p0lo;
  *reinterpret_cast<vf4*>(outp + 4)          = p0hi;
  *reinterpret_cast<vf4*>(outp + LENGTH)     = p1lo;
  *reinterpret_cast<vf4*>(outp + LENGTH + 4) = p1hi;
}

__global__ __launch_bounds__(NTHR, 4) void chain_bp_kernel(
    const float* __restrict__ jp, const float* __restrict__ bp,
    const int* __restrict__ obs, float* __restrict__ out) {
  const int rowA = blockIdx.x;
  const int rowB = blockIdx.x + GRID;
  const int tid  = threadIdx.x;
  const int lane = tid & 63;
  const int wv   = tid >> 6;

  // All potentials pre-scaled by log2(e): outputs use raw v_exp_f32 (2^x).
  const float LOG2E = 1.44269504088896f;
  const float j  = jp[0];
  const float q  = 0.25f * j * LOG2E;
  const float u0 = 0.5f * bp[0] * LOG2E;
  const float u1 = 0.5f * bp[1] * LOG2E;
  const float wb = -fabsf(q);              // 0vec == S (x) (wb,wb)

  __shared__ vf4 lut4s[16];
  __shared__ vf4 lut8[256];
  __shared__ float smpA[NWAVE][4], smsA[NWAVE][4];
  __shared__ float smpB[NWAVE][4], smsB[NWAVE][4];

  // ---- both rows' observations up front (loads overlap everything) ----
  const int t0 = tid * CHUNK;
  const int4* opA = reinterpret_cast<const int4*>(obs + (size_t)rowA * LENGTH + t0);
  const int4* opB = reinterpret_cast<const int4*>(obs + (size_t)rowB * LENGTH + t0);
  int4 a0v = opA[0], a1v = opA[1];
  int4 b0v = opB[0], b1v = opB[1];

  float uA[CHUNK], uB[CHUNK];
  uA[0]=a0v.x?u1:u0; uA[1]=a0v.y?u1:u0; uA[2]=a0v.z?u1:u0; uA[3]=a0v.w?u1:u0;
  uA[4]=a1v.x?u1:u0; uA[5]=a1v.y?u1:u0; uA[6]=a1v.z?u1:u0; uA[7]=a1v.w?u1:u0;
  uB[0]=b0v.x?u1:u0; uB[1]=b0v.y?u1:u0; uB[2]=b0v.z?u1:u0; uB[3]=b0v.w?u1:u0;
  uB[4]=b1v.x?u1:u0; uB[5]=b1v.y?u1:u0; uB[6]=b1v.z?u1:u0; uB[7]=b1v.w?u1:u0;
  int idxA = a0v.x | (a0v.y<<1) | (a0v.z<<2) | (a0v.w<<3)
           | (a1v.x<<4) | (a1v.y<<5) | (a1v.z<<6) | (a1v.w<<7);
  int idxB = b0v.x | (b0v.y<<1) | (b0v.z<<2) | (b0v.w<<3)
           | (b1v.x<<4) | (b1v.y<<5) | (b1v.z<<6) | (b1v.w<<7);

  // ---- LUT: 4-bit then 8-bit (shared by both rows) ----
  if (tid < 16) {
    float ua = (tid & 1) ? u1 : u0;
    float f00 = -ua + q, f01 = ua - q, f10 = -ua - q, f11 = ua + q;
#pragma unroll
    for (int k = 1; k < 4; ++k)
      mp_step(f00, f01, f10, f11, ((tid >> k) & 1) ? u1 : u0, q);
    lut4s[tid] = (vf4){f00, f01, f10, f11};
  }
  __syncthreads();
  if (tid < 256) {
    vf4 a = lut4s[tid >> 4], c = lut4s[tid & 15];
    float d00, d01, d10, d11;
    mp_compose(a[0], a[1], a[2], a[3], c[0], c[1], c[2], c[3], d00, d01, d10, d11);
    lut8[tid] = (vf4){d00, d01, d10, d11};
  }
  __syncthreads();

  vf4 FA = lut8[idxA];
  vf4 FB = lut8[idxB];

  // ---- interleaved wave scans for BOTH rows (prefix X, suffix Y=F^T) ----
  float xa00 = FA[0], xa01 = FA[1], xa10 = FA[2], xa11 = FA[3];
  float ya00 = FA[0], ya01 = FA[2], ya10 = FA[1], ya11 = FA[3];
  float xb00 = FB[0], xb01 = FB[1], xb10 = FB[2], xb11 = FB[3];
  float yb00 = FB[0], yb01 = FB[2], yb10 = FB[1], yb11 = FB[3];
#pragma unroll
  for (int d = 1; d < 64; d <<= 1) {
    float pa00 = __shfl_up(xa00, d), pa01 = __shfl_up(xa01, d);
    float pa10 = __shfl_up(xa10, d), pa11 = __shfl_up(xa11, d);
    float qa00 = __shfl_down(ya00, d), qa01 = __shfl_down(ya01, d);
    float qa10 = __shfl_down(ya10, d), qa11 = __shfl_down(ya11, d);
    float pb00 = __shfl_up(xb00, d), pb01 = __shfl_up(xb01, d);
    float pb10 = __shfl_up(xb10, d), pb11 = __shfl_up(xb11, d);
    float qb00 = __shfl_down(yb00, d), qb01 = __shfl_down(yb01, d);
    float qb10 = __shfl_down(yb10, d), qb11 = __shfl_down(yb11, d);
    if (lane >= d) {
      float n00, n01, n10, n11;
      mp_compose(xa00, xa01, xa10, xa11, pa00, pa01, pa10, pa11, n00, n01, n10, n11);
      xa00 = n00; xa01 = n01; xa10 = n10; xa11 = n11;
      mp_compose(xb00, xb01, xb10, xb11, pb00, pb01, pb10, pb11, n00, n01, n10, n11);
      xb00 = n00; xb01 = n01; xb10 = n10; xb11 = n11;
    }
    if (lane + d < 64) {
      float n00, n01, n10, n11;
      mp_compose(ya00, ya01, ya10, ya11, qa00, qa01, qa10, qa11, n00, n01, n10, n11);
      ya00 = n00; ya01 = n01; ya10 = n10; ya11 = n11;
      mp_compose(yb00, yb01, yb10, yb11, qb00, qb01, qb10, qb11, n00, n01, n10, n11);
      yb00 = n00; yb01 = n01; yb10 = n10; yb11 = n11;
    }
  }

  // ---- cross-wave stitch (one barrier serves both rows) ----
  if (lane == 63) {
    smpA[wv][0] = xa00; smpA[wv][1] = xa01; smpA[wv][2] = xa10; smpA[wv][3] = xa11;
    smpB[wv][0] = xb00; smpB[wv][1] = xb01; smpB[wv][2] = xb10; smpB[wv][3] = xb11;
  }
  if (lane == 0) {
    smsA[wv][0] = ya00; smsA[wv][1] = ya01; smsA[wv][2] = ya10; smsA[wv][3] = ya11;
    smsB[wv][0] = yb00; smsB[wv][1] = yb01; smsB[wv][2] = yb10; smsB[wv][3] = yb11;
  }
  __syncthreads();

  // ---- boundaries, row A ----
  float fiA0, fiA1, gA0, gA1;
  {
    float fh0 = 0.f, fh1 = 0.f;
    for (int k = 0; k < wv; ++k) {
      float n0 = fmaxf(smpA[k][0] + fh0, smpA[k][1] + fh1);
      float n1 = fmaxf(smpA[k][2] + fh0, smpA[k][3] + fh1);
      fh0 = n0; fh1 = n1;
    }
    float wt0 = wb, wt1 = wb;
    for (int k = NWAVE - 1; k > wv; --k) {
      float n0 = fmaxf(smsA[k][0] + wt0, smsA[k][1] + wt1);
      float n1 = fmaxf(smsA[k][2] + wt0, smsA[k][3] + wt1);
      wt0 = n0; wt1 = n1;
    }
    float z0 = fmaxf(xa00 + fh0, xa01 + fh1);
    float z1 = fmaxf(xa10 + fh0, xa11 + fh1);
    float zp0 = __shfl_up(z0, 1), zp1 = __shfl_up(z1, 1);
    fiA0 = (lane == 0) ? fh0 : zp0;
    fiA1 = (lane == 0) ? fh1 : zp1;
    float yv0 = fmaxf(ya00 + wt0, ya01 + wt1);
    float yv1 = fmaxf(ya10 + wt0, ya11 + wt1);
    float yn0 = __shfl_down(yv0, 1), yn1 = __shfl_down(yv1, 1);
    float wc0 = (lane == 63) ? wt0 : yn0;
    float wc1 = (lane == 63) ? wt1 : yn1;
    gA0 = fmaxf(q + wc0, -q + wc1);
    gA1 = fmaxf(-q + wc0, q + wc1);
  }
  // ---- boundaries, row B ----
  float fiB0, fiB1, gB0, gB1;
  {
    float fh0 = 0.f, fh1 = 0.f;
    for (int k = 0; k < wv; ++k) {
      float n0 = fmaxf(smpB[k][0] + fh0, smpB[k][1] + fh1);
      float n1 = fmaxf(smpB[k][2] + fh0, smpB[k][3] + fh1);
      fh0 = n0; fh1 = n1;
    }
    float wt0 = wb, wt1 = wb;
    for (int k = NWAVE - 1; k > wv; --k) {
      float n0 = fmaxf(smsB[k][0] + wt0, smsB[k][1] + wt1);
      float n1 = fmaxf(smsB[k][2] + wt0, smsB[k][3] + wt1);
      wt0 = n0; wt1 = n1;
    }
    float z0 = fmaxf(xb00 + fh0, xb01 + fh1);
    float z1 = fmaxf(xb10 + fh0, xb11 + fh1);
    float zp0 = __shfl_up(z0, 1), zp1 = __shfl_up(z1, 1);
    fiB0 = (lane == 0) ? fh0 : zp0;
    fiB1 = (lane == 0) ? fh1 : zp1;
    float yv0 = fmaxf(yb00 + wt0, yb01 + wt1);
    float yv1 = fmaxf(yb10 + wt0, yb11 + wt1);
    float yn0 = __shfl_down(yv0, 1), yn1 = __shfl_down(yv1, 1);
    float wc0 = (lane == 63) ? wt0 : yn0;
    float wc1 = (lane == 63) ? wt1 : yn1;
    gB0 = fmaxf(q + wc0, -q + wc1);
    gB1 = fmaxf(-q + wc0, q + wc1);
  }

  // ---- sweep + store row A (stores drain under row B's compute) ----
  sweep_store(uA, fiA0, fiA1, gA0, gA1, q,
              out + (size_t)rowA * (2 * LENGTH) + t0);
  // ---- sweep + store row B ----
  sweep_store(uB, fiB0, fiB1, gB0, gB1, q,
              out + (size_t)rowB * (2 * LENGTH) + t0);
}

extern "C" void kernel_launch(void* const* d_in, const int* in_sizes, int n_in,
                              void* d_out, int out_size, void* d_ws, size_t ws_size,
                              hipStream_t stream) {
  const float* jp  = (const float*)d_in[0];   // scalar j
  const float* bp  = (const float*)d_in[1];   // b[2]
  const int*   obs = (const int*)d_in[2];     // [BATCH, LENGTH] int32
  float* out = (float*)d_out;                 // [BATCH, 2, LENGTH] fp32

  chain_bp_kernel<<<GRID, NTHR, 0, stream>>>(jp, bp, obs, out);
}